// Round 10
// baseline (465.724 us; speedup 1.0000x reference)
//
#include <hip/hip_runtime.h>
#include <hip/hip_fp16.h>

#define FEAT 48
#define CH 12            // 12 lanes per node row, 4 fp16 feats (8B) each; 96B u rows
#define STEPS 10
#define BK 256           // nodes per bucket
#define NBMAX 512        // max buckets (N <= 131072)
#define CAP 5120         // edges capacity per bucket (mean 4096 at E=1.6M; +16 sigma)
#define DB 512           // degree bins for counting sort
constexpr float LAM   = 0.9f;
constexpr float OMLAM = 0.1f;

// --- setup: bucketed histogram + CSR build (no per-edge global atomics) ---

__global__ void setup_kernel(int* __restrict__ bcur, int* __restrict__ ccur, int nb,
                             const int* __restrict__ mask, int* __restrict__ winner, int M) {
    int i = blockIdx.x * blockDim.x + threadIdx.x;
    if (i < nb) { bcur[i] = i * CAP; ccur[i] = i * CAP; }
    if (i < M) atomicMax(&winner[mask[i]], i);
}

__global__ __launch_bounds__(1024)
void bucket_scatter(const int* __restrict__ row, const int* __restrict__ col,
                    int* __restrict__ bcur, int* __restrict__ ccur,
                    unsigned int* __restrict__ bstore, unsigned char* __restrict__ cstore,
                    int E, int nb, int nblk) {
    __shared__ int hr[NBMAX], cr[NBMAX], hc[NBMAX], cc[NBMAX];
    int tid = threadIdx.x;
    int ce = (E + nblk - 1) / nblk;
    int s = blockIdx.x * ce;
    int e_end = min(E, s + ce);
    for (int i = tid; i < nb; i += blockDim.x) { hr[i] = 0; hc[i] = 0; }
    __syncthreads();
    for (int i = s + tid; i < e_end; i += blockDim.x) {
        atomicAdd(&hr[row[i] >> 8], 1);
        atomicAdd(&hc[col[i] >> 8], 1);
    }
    __syncthreads();
    for (int i = tid; i < nb; i += blockDim.x) {
        cr[i] = hr[i] ? atomicAdd(&bcur[i], hr[i]) : 0;
        cc[i] = hc[i] ? atomicAdd(&ccur[i], hc[i]) : 0;
    }
    __syncthreads();
    for (int i = s + tid; i < e_end; i += blockDim.x) {
        int r = row[i], c = col[i];
        int pr = atomicAdd(&cr[r >> 8], 1);
        bstore[pr] = ((unsigned int)c << 8) | (unsigned int)(r & (BK - 1));
        int pc = atomicAdd(&cc[c >> 8], 1);
        cstore[pc] = (unsigned char)(c & (BK - 1));
    }
}

__global__ void bucket_prefix(const int* __restrict__ bcur, int* __restrict__ bpre,
                              int* __restrict__ off, int nb, int E, int N) {
    __shared__ int sh[NBMAX];
    int tid = threadIdx.x;
    int tot = (tid < nb) ? (bcur[tid] - tid * CAP) : 0;
    sh[tid] = tot;
    __syncthreads();
    for (int d = 1; d < NBMAX; d <<= 1) {
        int v = (tid >= d) ? sh[tid - d] : 0;
        __syncthreads();
        sh[tid] += v;
        __syncthreads();
    }
    if (tid < nb) bpre[tid] = sh[tid] - tot;
    if (tid == 0) off[N] = E;
}

// Phase B: per-bucket CSR finish + in-degree -> dinv + row out-degree
__global__ void finish_kernel(const unsigned int* __restrict__ bstore,
                              const int* __restrict__ bcur, const int* __restrict__ bpre,
                              const unsigned char* __restrict__ cstore,
                              const int* __restrict__ ccur,
                              int* __restrict__ off, int* __restrict__ csr_col,
                              float* __restrict__ dinv, int* __restrict__ rowdeg, int N) {
    __shared__ int h[BK], loc[BK], cur[BK];
    int b = blockIdx.x, tid = threadIdx.x;
    int cnt  = bcur[b] - b * CAP;
    int base = bpre[b];
    const unsigned int* src = bstore + (size_t)b * CAP;
    h[tid] = 0;
    __syncthreads();
    for (int i = tid; i < cnt; i += BK) atomicAdd(&h[src[i] & (BK - 1)], 1);
    __syncthreads();
    int v = h[tid];
    loc[tid] = v;
    __syncthreads();
    for (int d = 1; d < BK; d <<= 1) {
        int t = (tid >= d) ? loc[tid - d] : 0;
        __syncthreads();
        loc[tid] += t;
        __syncthreads();
    }
    int excl = loc[tid] - v;
    int r = b * BK + tid;
    if (r < N) { off[r] = base + excl; rowdeg[r] = v; }
    cur[tid] = excl;
    __syncthreads();
    for (int i = tid; i < cnt; i += BK) {
        unsigned int e = src[i];
        int p = atomicAdd(&cur[e & (BK - 1)], 1);
        csr_col[base + p] = (int)(e >> 8);
    }
    __syncthreads();
    h[tid] = 0;
    __syncthreads();
    int ccnt = ccur[b] - b * CAP;
    const unsigned char* csrc = cstore + (size_t)b * CAP;
    for (int i = tid; i < ccnt; i += BK) atomicAdd(&h[csrc[i]], 1);
    __syncthreads();
    int c = b * BK + tid;
    if (c < N) dinv[c] = (float)(1.0 / sqrt((double)h[tid]));
}

// --- counting sort of rows by out-degree (512 bins) -----------------------

__global__ void sort_hist(const int* __restrict__ rowdeg, int* __restrict__ dbin,
                          int N, int nblk) {
    __shared__ int h[DB];
    int tid = threadIdx.x;
    for (int i = tid; i < DB; i += blockDim.x) h[i] = 0;
    __syncthreads();
    int ce = (N + nblk - 1) / nblk;
    int s = blockIdx.x * ce, e = min(N, s + ce);
    for (int i = s + tid; i < e; i += blockDim.x)
        atomicAdd(&h[min(rowdeg[i], DB - 1)], 1);
    __syncthreads();
    for (int i = tid; i < DB; i += blockDim.x)
        if (h[i]) atomicAdd(&dbin[i], h[i]);
}

// rbase = excl scan of counts; ebase = excl scan of counts*deg; dcur = rbase
__global__ void sort_scan(const int* __restrict__ dbin, int* __restrict__ rbase,
                          int* __restrict__ ebase, int* __restrict__ dcur) {
    __shared__ int s1[DB], s2[DB];
    int tid = threadIdx.x;
    int c = dbin[tid];
    s1[tid] = c;
    s2[tid] = c * tid;
    __syncthreads();
    for (int d = 1; d < DB; d <<= 1) {
        int v1 = (tid >= d) ? s1[tid - d] : 0;
        int v2 = (tid >= d) ? s2[tid - d] : 0;
        __syncthreads();
        s1[tid] += v1; s2[tid] += v2;
        __syncthreads();
    }
    rbase[tid] = s1[tid] - c;
    ebase[tid] = s2[tid] - c * tid;
    dcur[tid]  = s1[tid] - c;
}

// scatter rows to sorted positions; emit perm, perm_inv, off2, dinv2
__global__ void sort_scatter(const int* __restrict__ rowdeg, const float* __restrict__ dinv,
                             int* __restrict__ dcur, const int* __restrict__ rbase,
                             const int* __restrict__ ebase,
                             int* __restrict__ perm, int* __restrict__ perm_inv,
                             int* __restrict__ off2, float* __restrict__ dinv2,
                             int N, int E, int nblk) {
    __shared__ int h[DB], cur[DB];
    int tid = threadIdx.x;
    for (int i = tid; i < DB; i += blockDim.x) h[i] = 0;
    __syncthreads();
    int ce = (N + nblk - 1) / nblk;
    int s = blockIdx.x * ce, e = min(N, s + ce);
    for (int i = s + tid; i < e; i += blockDim.x)
        atomicAdd(&h[min(rowdeg[i], DB - 1)], 1);
    __syncthreads();
    for (int i = tid; i < DB; i += blockDim.x)
        cur[i] = h[i] ? atomicAdd(&dcur[i], h[i]) : 0;
    __syncthreads();
    for (int i = s + tid; i < e; i += blockDim.x) {
        int deg = rowdeg[i];
        int b = min(deg, DB - 1);
        int pos = atomicAdd(&cur[b], 1);
        perm[pos] = i;
        perm_inv[i] = pos;
        off2[pos] = ebase[b] + (pos - rbase[b]) * deg;
        dinv2[pos] = dinv[i];
    }
    if (blockIdx.x == 0 && tid == 0) off2[N] = E;
}

// rebuild CSR in sorted row order with cols mapped to sorted space
__global__ void remap_kernel(const int* __restrict__ perm, const int* __restrict__ perm_inv,
                             const int* __restrict__ off, const int* __restrict__ off2,
                             const int* __restrict__ csr, int* __restrict__ csr2, int N) {
    int i = blockIdx.x * blockDim.x + threadIdx.x;
    if (i >= N) return;
    int r = perm[i];
    int sb = off[r], j0 = off2[i];
    int deg = off2[i + 1] - j0;
    for (int k = 0; k < deg; ++k)
        csr2[j0 + k] = perm_inv[csr[sb + k]];
}

// fused (sorted space): G'[i]=winner? Y:Z of row perm[i]; u0'[i]=fp16(dinv*G)
__global__ void prep_kernel(const float4* __restrict__ Z4, const float4* __restrict__ Y4,
                            const int* __restrict__ winner, const float* __restrict__ dinv2,
                            const int* __restrict__ perm,
                            float4* __restrict__ G4, uint2* __restrict__ u0, int N) {
    int t = blockIdx.x * blockDim.x + threadIdx.x;
    if (t >= N * CH) return;
    int i = t / CH, q = t - i * CH;
    int r = perm[i];
    int w = winner[r];
    float4 g = (w >= 0) ? Y4[(size_t)w * CH + q] : Z4[(size_t)r * CH + q];
    G4[t] = g;
    float d = dinv2[i];
    __half2 h0 = __floats2half2_rn(d * g.x, d * g.y);
    __half2 h1 = __floats2half2_rn(d * g.z, d * g.w);
    u0[t] = make_uint2(__builtin_bit_cast(unsigned int, h0),
                       __builtin_bit_cast(unsigned int, h1));
}

// --- diffusion step (sorted space; 12 lanes/row, 8B gathers, unroll 4) ----
#define ACC4(v)                                                                      \
    do {                                                                             \
        float2 f_;                                                                   \
        f_ = __half22float2(__builtin_bit_cast(__half2, (v).x)); ax += f_.x; ay += f_.y; \
        f_ = __half22float2(__builtin_bit_cast(__half2, (v).y)); az += f_.x; aw += f_.y; \
    } while (0)

template<bool LAST>
__global__ void diffuse_kernel(const uint2* __restrict__ up, const uint2* __restrict__ u0,
                               const float* __restrict__ dinv2, const float4* __restrict__ G4,
                               const int* __restrict__ off2, const int* __restrict__ cols,
                               const int* __restrict__ perm,
                               uint2* __restrict__ uout, float4* __restrict__ xout, int N) {
    int t = blockIdx.x * blockDim.x + threadIdx.x;
    if (t >= N * CH) return;
    int i = t / CH, q = t - i * CH;
    int j0 = off2[i], j1 = off2[i + 1];
    float ax = 0.f, ay = 0.f, az = 0.f, aw = 0.f;

    int j = j0;
    for (; j + 4 <= j1; j += 4) {
        int c0 = cols[j], c1 = cols[j + 1], c2 = cols[j + 2], c3 = cols[j + 3];
        uint2 v0 = up[(size_t)c0 * CH + q];
        uint2 v1 = up[(size_t)c1 * CH + q];
        uint2 v2 = up[(size_t)c2 * CH + q];
        uint2 v3 = up[(size_t)c3 * CH + q];
        ACC4(v0); ACC4(v1); ACC4(v2); ACC4(v3);
    }
    if (j < j1) {
        int c0 = cols[j];
        int c1 = (j + 1 < j1) ? cols[j + 1] : c0;
        int c2 = (j + 2 < j1) ? cols[j + 2] : c0;
        uint2 v0 = up[(size_t)c0 * CH + q];
        uint2 v1 = up[(size_t)c1 * CH + q];
        uint2 v2 = up[(size_t)c2 * CH + q];
        ACC4(v0);
        if (j + 1 < j1) ACC4(v1);
        if (j + 2 < j1) ACC4(v2);
    }

    float d = dinv2[i];
    if (LAST) {
        float4 g = G4[t];
        float4 o;
        float s = LAM * d;
        o.x = fmaf(s, ax, OMLAM * g.x);
        o.y = fmaf(s, ay, OMLAM * g.y);
        o.z = fmaf(s, az, OMLAM * g.z);
        o.w = fmaf(s, aw, OMLAM * g.w);
        xout[(size_t)perm[i] * CH + q] = o;   // one-time scatter back to original order
    } else {
        float a = LAM * d * d;
        uint2 z = u0[t];
        float2 b0 = __half22float2(__builtin_bit_cast(__half2, z.x));
        float2 b1 = __half22float2(__builtin_bit_cast(__half2, z.y));
        __half2 h0 = __floats2half2_rn(fmaf(a, ax, OMLAM * b0.x),
                                       fmaf(a, ay, OMLAM * b0.y));
        __half2 h1 = __floats2half2_rn(fmaf(a, az, OMLAM * b1.x),
                                       fmaf(a, aw, OMLAM * b1.y));
        uout[t] = make_uint2(__builtin_bit_cast(unsigned int, h0),
                             __builtin_bit_cast(unsigned int, h1));
    }
}

// --- launch --------------------------------------------------------------

extern "C" void kernel_launch(void* const* d_in, const int* in_sizes, int n_in,
                              void* d_out, int out_size, void* d_ws, size_t ws_size,
                              hipStream_t stream) {
    const float* Z    = (const float*)d_in[0];
    const float* Y    = (const float*)d_in[1];
    const int*   mask = (const int*)d_in[2];
    const int*   ei   = (const int*)d_in[3];

    const int N = in_sizes[0] / FEAT;
    const int M = in_sizes[2];
    const int E = in_sizes[3] / 2;
    const int* row = ei;
    const int* col = ei + E;
    const int NB = (N + BK - 1) / BK;

    char* ws = (char*)d_ws;
    size_t pos = 0;
    auto alloc = [&](size_t bytes) -> void* {
        void* p = ws + pos;
        pos = (pos + bytes + 255) & ~(size_t)255;
        return p;
    };
    float* G      = (float*)alloc((size_t)N * FEAT * 4);
    uint2* u0     = (uint2*)alloc((size_t)N * CH * 8);
    uint2* ua     = (uint2*)alloc((size_t)N * CH * 8);
    uint2* ub     = (uint2*)alloc((size_t)N * CH * 8);
    float* dinv   = (float*)alloc((size_t)N * 4);
    float* dinv2  = (float*)alloc((size_t)N * 4);
    int*   off    = (int*)  alloc((size_t)(N + 1) * 4);
    int*   off2   = (int*)  alloc((size_t)(N + 1) * 4);
    int*   winner = (int*)  alloc((size_t)N * 4);
    int*   rowdeg = (int*)  alloc((size_t)N * 4);
    int*   perm   = (int*)  alloc((size_t)N * 4);
    int*   pinv   = (int*)  alloc((size_t)N * 4);
    int*   csr    = (int*)  alloc((size_t)E * 4);
    int*   csr2   = (int*)  alloc((size_t)E * 4);
    unsigned int*  bstore = (unsigned int*) alloc((size_t)NB * CAP * 4);
    unsigned char* cstore = (unsigned char*)alloc((size_t)NB * CAP);
    int*   bcur   = (int*)  alloc((size_t)NBMAX * 4);
    int*   ccur   = (int*)  alloc((size_t)NBMAX * 4);
    int*   bpre   = (int*)  alloc((size_t)NBMAX * 4);
    int*   dbin   = (int*)  alloc((size_t)DB * 4);
    int*   rbase  = (int*)  alloc((size_t)DB * 4);
    int*   ebase  = (int*)  alloc((size_t)DB * 4);
    int*   dcur   = (int*)  alloc((size_t)DB * 4);

    hipMemsetAsync(winner, 0xFF, (size_t)N * 4, stream);
    hipMemsetAsync(dbin,   0,    (size_t)DB * 4, stream);

    const int B = 256;
    const int setup_n = max(NB, M);
    setup_kernel<<<(setup_n + B - 1) / B, B, 0, stream>>>(bcur, ccur, NB, mask, winner, M);

    const int SBLK = 256;
    bucket_scatter<<<SBLK, 1024, 0, stream>>>(row, col, bcur, ccur, bstore, cstore, E, NB, SBLK);
    bucket_prefix <<<1, NBMAX, 0, stream>>>(bcur, bpre, off, NB, E, N);
    finish_kernel <<<NB, BK, 0, stream>>>(bstore, bcur, bpre, cstore, ccur,
                                          off, csr, dinv, rowdeg, N);

    const int HBLK = 128;
    sort_hist   <<<HBLK, 256, 0, stream>>>(rowdeg, dbin, N, HBLK);
    sort_scan   <<<1, DB, 0, stream>>>(dbin, rbase, ebase, dcur);
    sort_scatter<<<HBLK, 256, 0, stream>>>(rowdeg, dinv, dcur, rbase, ebase,
                                           perm, pinv, off2, dinv2, N, E, HBLK);
    remap_kernel<<<(N + B - 1) / B, B, 0, stream>>>(perm, pinv, off, off2, csr, csr2, N);

    prep_kernel<<<(N * CH + B - 1) / B, B, 0, stream>>>((const float4*)Z, (const float4*)Y,
                                                        winner, dinv2, perm, (float4*)G, u0, N);

    // steps 0..8 fp16 ping-pong (sorted space), step 9 -> f32 d_out (scatter)
    const int nt = N * CH;
    const uint2* src = u0;
    uint2* bufs[2] = { ua, ub };
    for (int it = 0; it < STEPS - 1; ++it) {
        uint2* dst = bufs[it & 1];
        diffuse_kernel<false><<<(nt + B - 1) / B, B, 0, stream>>>(
            src, u0, dinv2, (const float4*)G, off2, csr2, perm, dst, nullptr, N);
        src = dst;
    }
    diffuse_kernel<true><<<(nt + B - 1) / B, B, 0, stream>>>(
        src, u0, dinv2, (const float4*)G, off2, csr2, perm, nullptr, (float4*)d_out, N);
}

// Round 11
// 420.661 us; speedup vs baseline: 1.1071x; 1.1071x over previous
//
#include <hip/hip_runtime.h>
#include <hip/hip_fp16.h>

#define FEAT 48
#define CH 12            // 12 lanes per node row, 4 fp16 feats (8B) each; 96B u rows
#define STEPS 10
#define BK 256           // nodes per bucket
#define NBMAX 512        // max buckets (N <= 131072)
#define CAP 5120         // edges capacity per bucket (mean 4096 at E=1.6M; +16 sigma)
constexpr float LAM   = 0.9f;
constexpr float OMLAM = 0.1f;

// --- setup: bucketed histogram + CSR build (no per-edge global atomics) ---

// fused: bucket cursor init + numpy last-write-wins winner
__global__ void setup_kernel(int* __restrict__ bcur, int* __restrict__ ccur, int nb,
                             const int* __restrict__ mask, int* __restrict__ winner, int M) {
    int i = blockIdx.x * blockDim.x + threadIdx.x;
    if (i < nb) { bcur[i] = i * CAP; ccur[i] = i * CAP; }
    if (i < M) atomicMax(&winner[mask[i]], i);
}

// Phase A: scatter packed (col<<8 | row_local) into row-buckets and col_local
// bytes into col-buckets. LDS histograms; ~200K global reservation atomics.
__global__ __launch_bounds__(1024)
void bucket_scatter(const int* __restrict__ row, const int* __restrict__ col,
                    int* __restrict__ bcur, int* __restrict__ ccur,
                    unsigned int* __restrict__ bstore, unsigned char* __restrict__ cstore,
                    int E, int nb, int nblk) {
    __shared__ int hr[NBMAX], cr[NBMAX], hc[NBMAX], cc[NBMAX];
    int tid = threadIdx.x;
    int ce = (E + nblk - 1) / nblk;
    int s = blockIdx.x * ce;
    int e_end = min(E, s + ce);
    for (int i = tid; i < nb; i += blockDim.x) { hr[i] = 0; hc[i] = 0; }
    __syncthreads();
    for (int i = s + tid; i < e_end; i += blockDim.x) {
        atomicAdd(&hr[row[i] >> 8], 1);
        atomicAdd(&hc[col[i] >> 8], 1);
    }
    __syncthreads();
    for (int i = tid; i < nb; i += blockDim.x) {
        cr[i] = hr[i] ? atomicAdd(&bcur[i], hr[i]) : 0;
        cc[i] = hc[i] ? atomicAdd(&ccur[i], hc[i]) : 0;
    }
    __syncthreads();
    for (int i = s + tid; i < e_end; i += blockDim.x) {
        int r = row[i], c = col[i];
        int pr = atomicAdd(&cr[r >> 8], 1);   // LDS cursor (absolute index)
        bstore[pr] = ((unsigned int)c << 8) | (unsigned int)(r & (BK - 1));
        int pc = atomicAdd(&cc[c >> 8], 1);
        cstore[pc] = (unsigned char)(c & (BK - 1));
    }
}

// exclusive prefix over bucket totals; also writes off[N] = E
__global__ void bucket_prefix(const int* __restrict__ bcur, int* __restrict__ bpre,
                              int* __restrict__ off, int nb, int E, int N) {
    __shared__ int sh[NBMAX];
    int tid = threadIdx.x;
    int tot = (tid < nb) ? (bcur[tid] - tid * CAP) : 0;
    sh[tid] = tot;
    __syncthreads();
    for (int d = 1; d < NBMAX; d <<= 1) {
        int v = (tid >= d) ? sh[tid - d] : 0;
        __syncthreads();
        sh[tid] += v;
        __syncthreads();
    }
    if (tid < nb) bpre[tid] = sh[tid] - tot;   // exclusive
    if (tid == 0) off[N] = E;
}

// Phase B (fused): per-bucket CSR finish + in-degree -> dinv, all in LDS
__global__ void finish_kernel(const unsigned int* __restrict__ bstore,
                              const int* __restrict__ bcur, const int* __restrict__ bpre,
                              const unsigned char* __restrict__ cstore,
                              const int* __restrict__ ccur,
                              int* __restrict__ off, int* __restrict__ csr_col,
                              float* __restrict__ dinv, int N) {
    __shared__ int h[BK], loc[BK], cur[BK];
    int b = blockIdx.x, tid = threadIdx.x;
    // ---- CSR segment (row-bucket) ----
    int cnt  = bcur[b] - b * CAP;
    int base = bpre[b];
    const unsigned int* src = bstore + (size_t)b * CAP;
    h[tid] = 0;
    __syncthreads();
    for (int i = tid; i < cnt; i += BK) atomicAdd(&h[src[i] & (BK - 1)], 1);
    __syncthreads();
    int v = h[tid];
    loc[tid] = v;
    __syncthreads();
    for (int d = 1; d < BK; d <<= 1) {
        int t = (tid >= d) ? loc[tid - d] : 0;
        __syncthreads();
        loc[tid] += t;
        __syncthreads();
    }
    int excl = loc[tid] - v;
    int r = b * BK + tid;
    if (r < N) off[r] = base + excl;
    cur[tid] = excl;
    __syncthreads();
    for (int i = tid; i < cnt; i += BK) {
        unsigned int e = src[i];
        int p = atomicAdd(&cur[e & (BK - 1)], 1);   // LDS
        csr_col[base + p] = (int)(e >> 8);
    }
    // ---- in-degree (col-bucket) ----
    __syncthreads();
    h[tid] = 0;
    __syncthreads();
    int ccnt = ccur[b] - b * CAP;
    const unsigned char* csrc = cstore + (size_t)b * CAP;
    for (int i = tid; i < ccnt; i += BK) atomicAdd(&h[csrc[i]], 1);
    __syncthreads();
    int c = b * BK + tid;
    if (c < N) dinv[c] = (float)(1.0 / sqrt((double)h[tid]));   // deg >= 1 guaranteed
}

// fused: G = winner>=0 ? Y[winner] : Z ; u0 = fp16(dinv * G)  (96B rows)
__global__ void prep_kernel(const float4* __restrict__ Z4, const float4* __restrict__ Y4,
                            const int* __restrict__ winner, const float* __restrict__ dinv,
                            float4* __restrict__ G4, uint2* __restrict__ u0, int N) {
    int t = blockIdx.x * blockDim.x + threadIdx.x;
    if (t >= N * CH) return;
    int r = t / CH, q = t - r * CH;
    int w = winner[r];
    float4 g = (w >= 0) ? Y4[(size_t)w * CH + q] : Z4[t];
    G4[t] = g;
    float d = dinv[r];
    __half2 h0 = __floats2half2_rn(d * g.x, d * g.y);
    __half2 h1 = __floats2half2_rn(d * g.z, d * g.w);
    u0[t] = make_uint2(__builtin_bit_cast(unsigned int, h0),
                       __builtin_bit_cast(unsigned int, h1));
}

// --- diffusion step (12 lanes/row, 8B gathers, 8-wide unroll for MLP) -----
#define ACC4(v)                                                                      \
    do {                                                                             \
        float2 f_;                                                                   \
        f_ = __half22float2(__builtin_bit_cast(__half2, (v).x)); ax += f_.x; ay += f_.y; \
        f_ = __half22float2(__builtin_bit_cast(__half2, (v).y)); az += f_.x; aw += f_.y; \
    } while (0)

template<bool LAST>
__global__ void diffuse_kernel(const uint2* __restrict__ up, const uint2* __restrict__ u0,
                               const float* __restrict__ dinv, const float4* __restrict__ G4,
                               const int* __restrict__ off, const int* __restrict__ cols,
                               uint2* __restrict__ uout, float4* __restrict__ xout, int N) {
    int t = blockIdx.x * blockDim.x + threadIdx.x;
    if (t >= N * CH) return;
    int r = t / CH, q = t - r * CH;
    int j0 = off[r], j1 = off[r + 1];
    float ax = 0.f, ay = 0.f, az = 0.f, aw = 0.f;

    int j = j0;
    for (; j + 8 <= j1; j += 8) {
        int c0 = cols[j],     c1 = cols[j + 1], c2 = cols[j + 2], c3 = cols[j + 3];
        int c4 = cols[j + 4], c5 = cols[j + 5], c6 = cols[j + 6], c7 = cols[j + 7];
        uint2 v0 = up[(size_t)c0 * CH + q];
        uint2 v1 = up[(size_t)c1 * CH + q];
        uint2 v2 = up[(size_t)c2 * CH + q];
        uint2 v3 = up[(size_t)c3 * CH + q];
        uint2 v4 = up[(size_t)c4 * CH + q];
        uint2 v5 = up[(size_t)c5 * CH + q];
        uint2 v6 = up[(size_t)c6 * CH + q];
        uint2 v7 = up[(size_t)c7 * CH + q];
        ACC4(v0); ACC4(v1); ACC4(v2); ACC4(v3);
        ACC4(v4); ACC4(v5); ACC4(v6); ACC4(v7);
    }
    if (j + 4 <= j1) {
        int c0 = cols[j], c1 = cols[j + 1], c2 = cols[j + 2], c3 = cols[j + 3];
        uint2 v0 = up[(size_t)c0 * CH + q];
        uint2 v1 = up[(size_t)c1 * CH + q];
        uint2 v2 = up[(size_t)c2 * CH + q];
        uint2 v3 = up[(size_t)c3 * CH + q];
        ACC4(v0); ACC4(v1); ACC4(v2); ACC4(v3);
        j += 4;
    }
    if (j < j1) {
        int c0 = cols[j];
        int c1 = (j + 1 < j1) ? cols[j + 1] : c0;
        int c2 = (j + 2 < j1) ? cols[j + 2] : c0;
        uint2 v0 = up[(size_t)c0 * CH + q];
        uint2 v1 = up[(size_t)c1 * CH + q];
        uint2 v2 = up[(size_t)c2 * CH + q];
        ACC4(v0);
        if (j + 1 < j1) ACC4(v1);
        if (j + 2 < j1) ACC4(v2);
    }

    float d = dinv[r];
    if (LAST) {
        float4 g = G4[t];
        float4 o;
        float s = LAM * d;
        o.x = fmaf(s, ax, OMLAM * g.x);
        o.y = fmaf(s, ay, OMLAM * g.y);
        o.z = fmaf(s, az, OMLAM * g.z);
        o.w = fmaf(s, aw, OMLAM * g.w);
        xout[t] = o;
    } else {
        float a = LAM * d * d;
        uint2 z = u0[t];
        float2 b0 = __half22float2(__builtin_bit_cast(__half2, z.x));
        float2 b1 = __half22float2(__builtin_bit_cast(__half2, z.y));
        __half2 h0 = __floats2half2_rn(fmaf(a, ax, OMLAM * b0.x),
                                       fmaf(a, ay, OMLAM * b0.y));
        __half2 h1 = __floats2half2_rn(fmaf(a, az, OMLAM * b1.x),
                                       fmaf(a, aw, OMLAM * b1.y));
        uout[t] = make_uint2(__builtin_bit_cast(unsigned int, h0),
                             __builtin_bit_cast(unsigned int, h1));
    }
}

// --- launch --------------------------------------------------------------

extern "C" void kernel_launch(void* const* d_in, const int* in_sizes, int n_in,
                              void* d_out, int out_size, void* d_ws, size_t ws_size,
                              hipStream_t stream) {
    const float* Z    = (const float*)d_in[0];
    const float* Y    = (const float*)d_in[1];
    const int*   mask = (const int*)d_in[2];
    const int*   ei   = (const int*)d_in[3];

    const int N = in_sizes[0] / FEAT;
    const int M = in_sizes[2];
    const int E = in_sizes[3] / 2;
    const int* row = ei;
    const int* col = ei + E;
    const int NB = (N + BK - 1) / BK;   // 391 buckets

    char* ws = (char*)d_ws;
    size_t pos = 0;
    auto alloc = [&](size_t bytes) -> void* {
        void* p = ws + pos;
        pos = (pos + bytes + 255) & ~(size_t)255;
        return p;
    };
    float* G      = (float*)alloc((size_t)N * FEAT * 4);
    uint2* u0     = (uint2*)alloc((size_t)N * CH * 8);
    uint2* ua     = (uint2*)alloc((size_t)N * CH * 8);
    uint2* ub     = (uint2*)alloc((size_t)N * CH * 8);
    float* dinv   = (float*)alloc((size_t)N * 4);
    int*   off    = (int*)  alloc((size_t)(N + 1) * 4);
    int*   winner = (int*)  alloc((size_t)N * 4);
    int*   csr    = (int*)  alloc((size_t)E * 4);
    unsigned int*  bstore = (unsigned int*) alloc((size_t)NB * CAP * 4);
    unsigned char* cstore = (unsigned char*)alloc((size_t)NB * CAP);
    int*   bcur   = (int*)  alloc((size_t)NBMAX * 4);
    int*   ccur   = (int*)  alloc((size_t)NBMAX * 4);
    int*   bpre   = (int*)  alloc((size_t)NBMAX * 4);

    hipMemsetAsync(winner, 0xFF, (size_t)N * 4, stream);

    const int B = 256;
    const int setup_n = max(NB, M);
    setup_kernel<<<(setup_n + B - 1) / B, B, 0, stream>>>(bcur, ccur, NB, mask, winner, M);

    const int SBLK = 256;
    bucket_scatter<<<SBLK, 1024, 0, stream>>>(row, col, bcur, ccur, bstore, cstore, E, NB, SBLK);
    bucket_prefix <<<1, NBMAX, 0, stream>>>(bcur, bpre, off, NB, E, N);
    finish_kernel <<<NB, BK, 0, stream>>>(bstore, bcur, bpre, cstore, ccur,
                                          off, csr, dinv, N);

    prep_kernel<<<(N * CH + B - 1) / B, B, 0, stream>>>((const float4*)Z, (const float4*)Y,
                                                        winner, dinv, (float4*)G, u0, N);

    // steps 0..8 fp16 ping-pong, step 9 -> f32 d_out
    const int nt = N * CH;
    const uint2* src = u0;
    uint2* bufs[2] = { ua, ub };
    for (int it = 0; it < STEPS - 1; ++it) {
        uint2* dst = bufs[it & 1];
        diffuse_kernel<false><<<(nt + B - 1) / B, B, 0, stream>>>(
            src, u0, dinv, (const float4*)G, off, csr, dst, nullptr, N);
        src = dst;
    }
    diffuse_kernel<true><<<(nt + B - 1) / B, B, 0, stream>>>(
        src, u0, dinv, (const float4*)G, off, csr, nullptr, (float4*)d_out, N);
}